// Round 3
// baseline (5130.072 us; speedup 1.0000x reference)
//
#include <hip/hip_runtime.h>

// Problem constants (SIZE=68, SSN=8 -> C=9, S1=69, BATCH=256)
#define C9     9
#define S1     69
#define JT     621            // C9*S1: one (class,pos) plane
#define NBATCH 256
#define NSTEP  68
#define QJ     4761           // 69*69   (Q j-stride, P s-major plane size)
#define QI     42849          // 9*69*69 (Q i-stride; also P batch stride)
#define BROW   42849          // 69 planes * 621 per-batch alpha
#define ALPHA_N (NBATCH*BROW)
#define QTFL   385664         // padded float count of one ws region
#define NEGINF (-__builtin_inff())

// float4 with 4-byte alignment guarantee: rows have odd stride 69 floats, so
// 16B alignment is impossible; gfx950 supports dword-aligned dwordx4.
typedef float float4u __attribute__((ext_vector_type(4), aligned(4)));

// ---------------------------------------------------------------------------
// qw: QW[j][s][i][t] = Q[j][i][s][t].  Puts the 9 i-values at stride 276 B
// from one base (immediate-offset friendly) and makes the s-advance a single
// pointer increment in the scan's inner loop.
__global__ void qw_kernel(const float* __restrict__ Q, float* __restrict__ QW)
{
  const int bl = blockIdx.x;           // j*69 + s
  const int j = bl / S1, s = bl - j*S1;
  float* dst = QW + (size_t)bl*JT;
  const float* src = Q + (size_t)j*QI + s*S1;
  for (int f = threadIdx.x; f < JT; f += 256){
    const int i = f / S1, t = f - i*S1;
    dst[f] = src[i*QJ + t];
  }
}

// ---------------------------------------------------------------------------
// qtrans: QT[c][t][i][s] = Q[c][i][s][t]  (coalesced backtrace Q reads)
__global__ void qtrans_kernel(const float* __restrict__ Q, float* __restrict__ QT)
{
  __shared__ float tile[69*70];
  const int pl = blockIdx.x;           // c*9 + i
  const int c = pl / 9, i = pl - c*9;
  const float* src = Q + (size_t)pl*QJ;
  for (int f = threadIdx.x; f < QJ; f += 256){
    const int s = f / S1, t = f - s*S1;
    tile[s*70 + t] = src[f];
  }
  __syncthreads();
  float* dst = QT + (size_t)c*QI + i*S1;     // + t*621 + s
  for (int f = threadIdx.x; f < QJ; f += 256){
    const int t = f / S1, s = f - t*S1;
    dst[t*JT + s] = tile[s*70 + t];
  }
}

// ---------------------------------------------------------------------------
// mega v3: one batch per block, grid 256.  704 threads = 11 waves:
// 4 s-groups x 162 (j,t-quad) slots; FIXED 18-wide s-ranges
// [0,18) [17,35) [34,52) [51,69) (overlap rows duplicated -- max is
// idempotent, bit-identical).  Fixed trip count -> full unroll -> LLVM
// software-pipelines the immediate-offset QW loads.  Two barriers per step;
// lse finalize deferred to a post-loop pass via sums_sh.
__global__ __launch_bounds__(704) void mega_kernel(
    const float* __restrict__ P, const float* __restrict__ Q,
    const float* __restrict__ pi, const float* __restrict__ Tp,
    const int* __restrict__ ls, float* __restrict__ out,
    const float* __restrict__ QW, const float* __restrict__ QT, int wsmode)
{
  __shared__ __align__(16) float la[2][C9*72];   // la[buf][i*72 + s]
  __shared__ float part[3][162][4];              // groups 1..3 partial maxes
  __shared__ float red[11];
  __shared__ float m_sh[NSTEP+1], lse_sh[NSTEP+1], n_sh[NSTEP+1];
  __shared__ float sums_sh[NSTEP+1][3];          // per-(k, g0-wave) exp sums
  __shared__ float sbest[11];
  __shared__ int   sidx[11];
  __shared__ int   sct[2];

  const int tid  = threadIdx.x;
  const int w    = tid >> 6;
  const int lane = tid & 63;
  const int b    = blockIdx.x;
  const bool act = tid < 648;
  const int gg   = act ? tid / 162 : 3;          // s-group 0..3
  const int slot = act ? tid - gg*162 : 0;
  const int j    = slot / 18;                    // output class 0..8
  const int tq   = slot - j*18;                  // t-quad 0..17
  const int t0   = (tq < 17) ? 4*tq : 65;        // tq=17 owns only t=68
  const int s_lo = 17*gg;                        // fixed 18-wide (overlapped)
  const float Tv = Tp[0];

  float* outb = out + (size_t)b*BROW;

  // ---- prep: v[0] raw (pi at s==0, else -inf); m[0], lse_v[0] ----
  for (int e = tid; e < JT; e += 704){
    const int i = e / S1, s = e - i*S1;
    const float v0 = (s == 0) ? pi[i] : NEGINF;
    outb[68*JT + e] = v0;
    la[0][i*72 + s] = v0;
  }
  if (tid == 0){
    float mx = pi[0];
    #pragma unroll
    for (int c = 1; c < C9; ++c) mx = fmaxf(mx, pi[c]);
    float sm = 0.f;
    #pragma unroll
    for (int c = 0; c < C9; ++c) sm += expf(pi[c] - mx);
    m_sh[0]   = mx;
    lse_sh[0] = mx + logf(sm);
  }
  __syncthreads();
  float mprev = m_sh[0];

  const bool useQW = (wsmode >= 1);
  const float* qsw = QW + ((size_t)(j*S1 + s_lo)*C9)*S1 + t0;  // +d*JT +i*S1
  const float* qsr = Q + (size_t)j*QJ + s_lo*S1 + t0;          // +i*QI +d*S1
  const float* ps  = P + (size_t)(b*C9 + j)*QJ + s_lo*S1 + t0; // +d*S1

  // ---- 68 max-plus steps ----
  int cur = 0;
  for (int k = 1; k <= NSTEP; ++k){
    const float* laC = la[cur];
    float a0 = NEGINF, a1 = NEGINF, a2 = NEGINF, a3 = NEGINF;
    if (act){
      if (useQW){
        #pragma unroll
        for (int d = 0; d < 18; ++d){
          float4u q[C9];
          #pragma unroll
          for (int i = 0; i < C9; ++i) q[i] = *(const float4u*)(qsw + d*JT + i*S1);
          const float4u pv = *(const float4u*)(ps + d*S1);
          float r0=NEGINF, r1=NEGINF, r2=NEGINF, r3=NEGINF;
          #pragma unroll
          for (int i = 0; i < C9; ++i){
            const float lv = laC[i*72 + s_lo + d];
            r0 = fmaxf(r0, fmaf(Tv, q[i].x, lv));
            r1 = fmaxf(r1, fmaf(Tv, q[i].y, lv));
            r2 = fmaxf(r2, fmaf(Tv, q[i].z, lv));
            r3 = fmaxf(r3, fmaf(Tv, q[i].w, lv));
          }
          a0 = fmaxf(a0, pv.x + r0);
          a1 = fmaxf(a1, pv.y + r1);
          a2 = fmaxf(a2, pv.z + r2);
          a3 = fmaxf(a3, pv.w + r3);
        }
      } else {
        #pragma unroll
        for (int d = 0; d < 18; ++d){
          float4u q[C9];
          #pragma unroll
          for (int i = 0; i < C9; ++i) q[i] = *(const float4u*)(qsr + i*QI + d*S1);
          const float4u pv = *(const float4u*)(ps + d*S1);
          float r0=NEGINF, r1=NEGINF, r2=NEGINF, r3=NEGINF;
          #pragma unroll
          for (int i = 0; i < C9; ++i){
            const float lv = laC[i*72 + s_lo + d];
            r0 = fmaxf(r0, fmaf(Tv, q[i].x, lv));
            r1 = fmaxf(r1, fmaf(Tv, q[i].y, lv));
            r2 = fmaxf(r2, fmaf(Tv, q[i].z, lv));
            r3 = fmaxf(r3, fmaf(Tv, q[i].w, lv));
          }
          a0 = fmaxf(a0, pv.x + r0);
          a1 = fmaxf(a1, pv.y + r1);
          a2 = fmaxf(a2, pv.z + r2);
          a3 = fmaxf(a3, pv.w + r3);
        }
      }
      if (gg > 0){
        part[gg-1][slot][0] = a0; part[gg-1][slot][1] = a1;
        part[gg-1][slot][2] = a2; part[gg-1][slot][3] = a3;
      }
    }
    __syncthreads();                                     // (A) partials ready

    float mval = NEGINF;
    float v0 = 0.f, v1 = 0.f, v2 = 0.f, v3 = 0.f;
    if (act && gg == 0){
      v0 = fmaxf(fmaxf(a0, part[0][slot][0]),
                 fmaxf(part[1][slot][0], part[2][slot][0])) - mprev;
      v1 = fmaxf(fmaxf(a1, part[0][slot][1]),
                 fmaxf(part[1][slot][1], part[2][slot][1])) - mprev;
      v2 = fmaxf(fmaxf(a2, part[0][slot][2]),
                 fmaxf(part[1][slot][2], part[2][slot][2])) - mprev;
      v3 = fmaxf(fmaxf(a3, part[0][slot][3]),
                 fmaxf(part[1][slot][3], part[2][slot][3])) - mprev;
      float* dst = outb + (size_t)(68-k)*JT + j*S1 + t0;
      if (tq < 17){
        float4u vv; vv.x = v0; vv.y = v1; vv.z = v2; vv.w = v3;
        *(float4u*)dst = vv;
        *(float4*)(&la[cur^1][j*72 + t0]) = make_float4(v0, v1, v2, v3);
        mval = fmaxf(fmaxf(v0, v1), fmaxf(v2, v3));
      } else {                                           // owns only t=68
        dst[3] = v3;
        la[cur^1][j*72 + 68] = v3;
        mval = v3;
      }
    }
    // block max -> m[k]  (only g0 waves 0..2 hold real values)
    float mr = mval;
    #pragma unroll
    for (int o = 32; o >= 1; o >>= 1) mr = fmaxf(mr, __shfl_down(mr, o));
    if (lane == 0) red[w] = mr;
    __syncthreads();                                     // (B) red + la ready
    const float mA = fmaxf(fmaxf(red[0], red[1]), red[2]);
    if (act && gg == 0){
      float sv = (tq < 17)
        ? expf(v0 - mA) + expf(v1 - mA) + expf(v2 - mA) + expf(v3 - mA)
        : expf(v3 - mA);
      #pragma unroll
      for (int o = 32; o >= 1; o >>= 1) sv += __shfl_down(sv, o);
      if (lane == 0) sums_sh[k][w] = sv;
    }
    if (tid == 0) m_sh[k] = mA;
    mprev = mA;
    cur ^= 1;
  }
  __syncthreads();

  // ---- lse finalize + n[k] = lse_v[k] + D[k], D[k]=sum_{kk<k} m (double) ----
  if (tid == 0){
    double dd = 0.0;
    for (int kk = 0; kk <= NSTEP; ++kk){
      float lse;
      if (kk == 0) lse = lse_sh[0];
      else lse = m_sh[kk] + logf(sums_sh[kk][0] + sums_sh[kk][1] + sums_sh[kk][2]);
      lse_sh[kk] = lse;
      n_sh[kk] = (float)((double)lse + dd);
      dd += (double)m_sh[kk];
    }
  }
  __syncthreads();

  // ---- addc: alpha[K] = v[68-K] + (n[K] - lse_v[68-K]), clamp -3e38 ----
  for (int K = 0; K <= NSTEP; ++K){
    const float Cst = n_sh[K] - lse_sh[68-K];
    for (int e = tid; e < JT; e += 704){
      float* r = outb + (size_t)K*JT + e;
      *r = fmaxf(*r + Cst, -3.0e38f);
    }
  }
  __syncthreads();

  // ---- backtrace: 621 candidates, one per thread ----
  {
    int c = 3, t2 = ls[b];
    float* mpb = out + (size_t)ALPHA_N + (size_t)b*(69*3);
    if (tid == 0){
      mpb[68*3+0] = 3.f; mpb[68*3+1] = 0.f; mpb[68*3+2] = (float)t2;
      mpb[67*3+1] = 0.f;   // l_0 = 0 after the shift
    }
    const bool vok = tid < JT;
    const int etid = vok ? tid : 0;
    const int im = etid / S1;
    const int sm = etid - im*S1;
    float av = vok ? outb[1*JT + tid] : NEGINF;
    for (int r = 1; r <= NSTEP; ++r){
      float avn = NEGINF;
      if (r < NSTEP && vok) avn = outb[(size_t)(r+1)*JT + tid];
      float best = NEGINF; int bidx = 0x7fffffff;
      if (vok){
        float qv;
        if (wsmode >= 2)      qv = QT[(size_t)c*QI + (size_t)t2*JT + tid];
        else if (wsmode == 1) qv = QW[((size_t)(c*S1 + sm)*C9 + im)*S1 + t2];
        else                  qv = Q[(size_t)c*QI + (size_t)im*QJ + sm*S1 + t2];
        const float pv = P[(size_t)(b*C9 + c)*QJ + sm*S1 + t2];
        best = (pv + Tv*qv) + av;   // exact ref association
        bidx = tid;
      }
      // argmax: strict > with min-index tie-break == jnp.argmax first-occurrence
      #pragma unroll
      for (int o = 32; o >= 1; o >>= 1){
        const float ov = __shfl_down(best, o); const int oi = __shfl_down(bidx, o);
        if (ov > best || (ov == best && oi < bidx)){ best = ov; bidx = oi; }
      }
      if (lane == 0){ sbest[w] = best; sidx[w] = bidx; }
      __syncthreads();
      if (tid == 0){
        float bb = sbest[0]; int bi = sidx[0];
        #pragma unroll
        for (int q = 1; q < 11; ++q)
          if (sbest[q] > bb || (sbest[q] == bb && sidx[q] < bi)){
            bb = sbest[q]; bi = sidx[q];
          }
        const int cn = bi / S1, tn = bi - cn*S1;
        mpb[(68-r)*3 + 0] = (float)cn;
        mpb[(68-r)*3 + 2] = (float)tn;
        if (r <= 67) mpb[(67-r)*3 + 1] = (float)(tn - t2);
        sct[0] = cn; sct[1] = tn;
      }
      __syncthreads();
      c = sct[0]; t2 = sct[1];
      av = avn;
    }
  }
}

// ---------------------------------------------------------------------------
extern "C" void kernel_launch(void* const* d_in, const int* in_sizes, int n_in,
                              void* d_out, int out_size, void* d_ws, size_t ws_size,
                              hipStream_t stream)
{
  const float* P  = (const float*)d_in[0];
  const float* Q  = (const float*)d_in[1];
  const float* pi = (const float*)d_in[2];
  const float* T  = (const float*)d_in[3];
  const int*   ls = (const int*)d_in[4];

  float* out = (float*)d_out;

  // ws regions (launch-invariant branches -> graph-safe):
  //   [0, QTFL)        QW  (scan-optimized Q layout)
  //   [QTFL, 2*QTFL)   QT  (backtrace-coalesced Q layout)
  int wsmode = 0; float* QW = nullptr; float* QT = nullptr;
  if (ws_size >= (size_t)QTFL*4){ wsmode = 1; QW = (float*)d_ws; }
  if (ws_size >= (size_t)2*QTFL*4){ wsmode = 2; QT = (float*)d_ws + QTFL; }

  if (wsmode >= 1) qw_kernel<<<JT, 256, 0, stream>>>(Q, QW);
  if (wsmode >= 2) qtrans_kernel<<<81, 256, 0, stream>>>(Q, QT);
  mega_kernel<<<NBATCH, 704, 0, stream>>>(P, Q, pi, T, ls, out, QW, QT, wsmode);
}

// Round 4
// 2218.424 us; speedup vs baseline: 2.3125x; 2.3125x over previous
//
#include <hip/hip_runtime.h>

// Problem constants (SIZE=68, SSN=8 -> C=9, S1=69, BATCH=256)
#define C9     9
#define S1     69
#define JT     621            // C9*S1: one (class,pos) plane
#define NBATCH 256
#define NSTEP  68
#define QJ     4761           // 69*69   (Q j-stride, P s-major plane size)
#define QI     42849          // 9*69*69 (Q i-stride; also P batch stride)
#define BROW   42849          // 69 planes * 621 per-batch alpha
#define ALPHA_N (NBATCH*BROW)
#define QTFL   385664         // padded float count of one ws region
#define NEGINF (-__builtin_inff())

// float4 with 4-byte alignment guarantee: rows have odd stride 69 floats, so
// 16B alignment is impossible; gfx950 supports dword-aligned dwordx4.
typedef float float4u __attribute__((ext_vector_type(4), aligned(4)));

// ---------------------------------------------------------------------------
// qw: QW[j][s][i][t] = Q[j][i][s][t].  Puts the 9 i-values at stride 276 B
// from one base (13-bit immediate-offset friendly: one shared address reg)
// and makes the s-advance a single pointer increment in the scan inner loop.
__global__ void qw_kernel(const float* __restrict__ Q, float* __restrict__ QW)
{
  const int bl = blockIdx.x;           // j*69 + s
  const int j = bl / S1, s = bl - j*S1;
  float* dst = QW + (size_t)bl*JT;
  const float* src = Q + (size_t)j*QJ + s*S1;
  for (int f = threadIdx.x; f < JT; f += 256){
    const int i = f / S1, t = f - i*S1;
    dst[f] = src[i*QJ + t];
  }
}

// ---------------------------------------------------------------------------
// qtrans: QT[c][t][i][s] = Q[c][i][s][t]  (coalesced backtrace Q reads)
__global__ void qtrans_kernel(const float* __restrict__ Q, float* __restrict__ QT)
{
  __shared__ float tile[69*70];
  const int pl = blockIdx.x;           // c*9 + i
  const int c = pl / 9, i = pl - c*9;
  const float* src = Q + (size_t)pl*QJ;
  for (int f = threadIdx.x; f < QJ; f += 256){
    const int s = f / S1, t = f - s*S1;
    tile[s*70 + t] = src[f];
  }
  __syncthreads();
  float* dst = QT + (size_t)c*QI + i*S1;     // + t*621 + s
  for (int f = threadIdx.x; f < QJ; f += 256){
    const int t = f / S1, s = f - t*S1;
    dst[t*JT + s] = tile[s*70 + t];
  }
}

// ---------------------------------------------------------------------------
// scan12: partial max-plus over 12 consecutive s rows (caller pre-offsets all
// bases by s_lo).  SI = Q i-stride (floats), SS = Q s-stride (floats).
// ROLLED loop + explicit 2-deep ping-pong: round-2-proven register footprint
// (round 3's full unroll spilled to scratch -- 4x TCC traffic; never again).
template<int SI, int SS>
__device__ __forceinline__ float4u scan12(const float* __restrict__ qb,
                                          const float* __restrict__ pb,
                                          const float* __restrict__ laS,
                                          const float Tv)
{
#define LD(BUF, PV, S) { \
  const float* q_ = qb + (S)*SS; \
  _Pragma("unroll") \
  for (int i_ = 0; i_ < C9; ++i_) BUF[i_] = *(const float4u*)(q_ + i_*SI); \
  PV = *(const float4u*)(pb + (S)*S1); }
#define CM(BUF, PV, S) { \
  float r0=NEGINF, r1=NEGINF, r2=NEGINF, r3=NEGINF; \
  _Pragma("unroll") \
  for (int i_ = 0; i_ < C9; ++i_){ \
    const float lv_ = laS[i_*72 + (S)]; \
    r0 = fmaxf(r0, fmaf(Tv, BUF[i_].x, lv_)); \
    r1 = fmaxf(r1, fmaf(Tv, BUF[i_].y, lv_)); \
    r2 = fmaxf(r2, fmaf(Tv, BUF[i_].z, lv_)); \
    r3 = fmaxf(r3, fmaf(Tv, BUF[i_].w, lv_)); \
  } \
  acc.x = fmaxf(acc.x, PV.x + r0); acc.y = fmaxf(acc.y, PV.y + r1); \
  acc.z = fmaxf(acc.z, PV.z + r2); acc.w = fmaxf(acc.w, PV.w + r3); }

  float4u acc; acc.x = acc.y = acc.z = acc.w = NEGINF;
  float4u qA[C9], qB[C9], pA, pB;
  int s = 0;
  LD(qA, pA, s)
  for (; s + 2 < 12; s += 2){
    LD(qB, pB, s+1)
    CM(qA, pA, s)
    LD(qA, pA, s+2)
    CM(qB, pB, s+1)
  }
  // width 12 is even: epilogue handles the final pair
  LD(qB, pB, s+1)
  CM(qA, pA, s)
  CM(qB, pB, s+1)
  return acc;
#undef LD
#undef CM
}

// ---------------------------------------------------------------------------
// mega v4: one batch per block, grid 256.  1024 threads = 16 waves (4/SIMD):
// 6 s-groups x 162 (j,t-quad) slots; fixed 12-wide s-ranges starting at
// {0,11,23,34,46,57} (overlap rows duplicated -- max idempotent, exact).
// Two barriers per step; lse finalize deferred via sums_sh.
__global__ __launch_bounds__(1024) void mega_kernel(
    const float* __restrict__ P, const float* __restrict__ Q,
    const float* __restrict__ pi, const float* __restrict__ Tp,
    const int* __restrict__ ls, float* __restrict__ out,
    const float* __restrict__ QW, const float* __restrict__ QT, int wsmode)
{
  __shared__ __align__(16) float la[2][C9*72];   // la[buf][i*72 + s]
  __shared__ float part[5][162][4];              // groups 1..5 partial maxes
  __shared__ float red[16];
  __shared__ float m_sh[NSTEP+1], lse_sh[NSTEP+1], n_sh[NSTEP+1];
  __shared__ float sums_sh[NSTEP+1][3];          // per-(k, g0-wave) exp sums
  __shared__ float sbest[16];
  __shared__ int   sidx[16];
  __shared__ int   sct[2];

  const int tid  = threadIdx.x;
  const int w    = tid >> 6;
  const int lane = tid & 63;
  const int b    = blockIdx.x;
  const bool act = tid < 972;
  const int gg   = act ? tid / 162 : 5;          // s-group 0..5
  const int slot = act ? tid - gg*162 : 0;
  const int j    = slot / 18;                    // output class 0..8
  const int tq   = slot - j*18;                  // t-quad 0..17
  const int t0   = (tq < 17) ? 4*tq : 65;        // tq=17 owns only t=68
  const int s_lo = (gg*23) >> 1;                 // {0,11,23,34,46,57}
  const float Tv = Tp[0];

  float* outb = out + (size_t)b*BROW;

  // ---- prep: v[0] raw (pi at s==0, else -inf); m[0], lse_v[0] ----
  for (int e = tid; e < JT; e += 1024){
    const int i = e / S1, s = e - i*S1;
    const float v0 = (s == 0) ? pi[i] : NEGINF;
    outb[68*JT + e] = v0;
    la[0][i*72 + s] = v0;
  }
  if (tid == 0){
    float mx = pi[0];
    #pragma unroll
    for (int c = 1; c < C9; ++c) mx = fmaxf(mx, pi[c]);
    float sm = 0.f;
    #pragma unroll
    for (int c = 0; c < C9; ++c) sm += expf(pi[c] - mx);
    m_sh[0]   = mx;
    lse_sh[0] = mx + logf(sm);
  }
  __syncthreads();
  float mprev = m_sh[0];

  const bool useQW = (wsmode >= 1);
  // QW[j][s][i][t]: j-stride S1*JT == QI; s-stride JT; i-stride S1.
  const float* qw_b = QW + (size_t)j*QI + (size_t)s_lo*JT + t0;
  // Raw Q[j][i][s][t]: i-stride QI; s-stride S1.
  const float* qr_b = Q + (size_t)j*QJ + s_lo*S1 + t0;
  const float* p_b  = P + (size_t)(b*C9 + j)*QJ + s_lo*S1 + t0;

  // ---- 68 max-plus steps ----
  int cur = 0;
  for (int k = 1; k <= NSTEP; ++k){
    const float* laS = la[cur] + s_lo;
    float4u acc;
    if (act){
      if (useQW) acc = scan12<S1, JT>(qw_b, p_b, laS, Tv);
      else       acc = scan12<QI, S1>(qr_b, p_b, laS, Tv);
      if (gg > 0){
        part[gg-1][slot][0] = acc.x; part[gg-1][slot][1] = acc.y;
        part[gg-1][slot][2] = acc.z; part[gg-1][slot][3] = acc.w;
      }
    }
    __syncthreads();                                     // (A) partials ready

    float mval = NEGINF;
    float v0 = 0.f, v1 = 0.f, v2 = 0.f, v3 = 0.f;
    if (act && gg == 0){
      float c0 = acc.x, c1 = acc.y, c2 = acc.z, c3 = acc.w;
      #pragma unroll
      for (int g = 0; g < 5; ++g){
        c0 = fmaxf(c0, part[g][slot][0]);
        c1 = fmaxf(c1, part[g][slot][1]);
        c2 = fmaxf(c2, part[g][slot][2]);
        c3 = fmaxf(c3, part[g][slot][3]);
      }
      v0 = c0 - mprev; v1 = c1 - mprev; v2 = c2 - mprev; v3 = c3 - mprev;
      float* dst = outb + (size_t)(68-k)*JT + j*S1 + t0;
      if (tq < 17){
        float4u vv; vv.x = v0; vv.y = v1; vv.z = v2; vv.w = v3;
        *(float4u*)dst = vv;
        *(float4*)(&la[cur^1][j*72 + t0]) = make_float4(v0, v1, v2, v3);
        mval = fmaxf(fmaxf(v0, v1), fmaxf(v2, v3));
      } else {                                           // owns only t=68
        dst[3] = v3;
        la[cur^1][j*72 + 68] = v3;
        mval = v3;
      }
    }
    // block max -> m[k]  (only g0 waves 0..2 hold real values)
    float mr = mval;
    #pragma unroll
    for (int o = 32; o >= 1; o >>= 1) mr = fmaxf(mr, __shfl_down(mr, o));
    if (lane == 0) red[w] = mr;
    __syncthreads();                                     // (B) red + la ready
    const float mA = fmaxf(fmaxf(red[0], red[1]), red[2]);
    if (act && gg == 0){
      float sv = (tq < 17)
        ? expf(v0 - mA) + expf(v1 - mA) + expf(v2 - mA) + expf(v3 - mA)
        : expf(v3 - mA);
      #pragma unroll
      for (int o = 32; o >= 1; o >>= 1) sv += __shfl_down(sv, o);
      if (lane == 0) sums_sh[k][w] = sv;
    }
    if (tid == 0) m_sh[k] = mA;
    mprev = mA;
    cur ^= 1;
  }
  __syncthreads();

  // ---- lse finalize + n[k] = lse_v[k] + D[k], D[k]=sum_{kk<k} m (double) ----
  if (tid == 0){
    double dd = 0.0;
    for (int kk = 0; kk <= NSTEP; ++kk){
      float lse;
      if (kk == 0) lse = lse_sh[0];
      else lse = m_sh[kk] + logf(sums_sh[kk][0] + sums_sh[kk][1] + sums_sh[kk][2]);
      lse_sh[kk] = lse;
      n_sh[kk] = (float)((double)lse + dd);
      dd += (double)m_sh[kk];
    }
  }
  __syncthreads();

  // ---- addc: alpha[K] = v[68-K] + (n[K] - lse_v[68-K]), clamp -3e38 ----
  for (int K = 0; K <= NSTEP; ++K){
    const float Cst = n_sh[K] - lse_sh[68-K];
    for (int e = tid; e < JT; e += 1024){
      float* r = outb + (size_t)K*JT + e;
      *r = fmaxf(*r + Cst, -3.0e38f);
    }
  }
  __syncthreads();

  // ---- backtrace: 621 candidates, one per thread ----
  {
    int c = 3, t2 = ls[b];
    float* mpb = out + (size_t)ALPHA_N + (size_t)b*(69*3);
    if (tid == 0){
      mpb[68*3+0] = 3.f; mpb[68*3+1] = 0.f; mpb[68*3+2] = (float)t2;
      mpb[67*3+1] = 0.f;   // l_0 = 0 after the shift
    }
    const bool vok = tid < JT;
    const int etid = vok ? tid : 0;
    const int im = etid / S1;
    const int sm = etid - im*S1;
    float av = vok ? outb[1*JT + tid] : NEGINF;
    for (int r = 1; r <= NSTEP; ++r){
      float avn = NEGINF;
      if (r < NSTEP && vok) avn = outb[(size_t)(r+1)*JT + tid];
      float best = NEGINF; int bidx = 0x7fffffff;
      if (vok){
        float qv;
        if (wsmode >= 2)      qv = QT[(size_t)c*QI + (size_t)t2*JT + tid];
        else if (wsmode == 1) qv = QW[(size_t)c*QI + (size_t)sm*JT + im*S1 + t2];
        else                  qv = Q[(size_t)c*QI + (size_t)im*QJ + sm*S1 + t2];
        const float pv = P[(size_t)(b*C9 + c)*QJ + sm*S1 + t2];
        best = (pv + Tv*qv) + av;   // exact ref association
        bidx = tid;
      }
      // argmax: strict > with min-index tie-break == jnp.argmax first-occurrence
      #pragma unroll
      for (int o = 32; o >= 1; o >>= 1){
        const float ov = __shfl_down(best, o); const int oi = __shfl_down(bidx, o);
        if (ov > best || (ov == best && oi < bidx)){ best = ov; bidx = oi; }
      }
      if (lane == 0){ sbest[w] = best; sidx[w] = bidx; }
      __syncthreads();
      if (tid == 0){
        float bb = sbest[0]; int bi = sidx[0];
        #pragma unroll
        for (int q = 1; q < 16; ++q)
          if (sbest[q] > bb || (sbest[q] == bb && sidx[q] < bi)){
            bb = sbest[q]; bi = sidx[q];
          }
        const int cn = bi / S1, tn = bi - cn*S1;
        mpb[(68-r)*3 + 0] = (float)cn;
        mpb[(68-r)*3 + 2] = (float)tn;
        if (r <= 67) mpb[(67-r)*3 + 1] = (float)(tn - t2);
        sct[0] = cn; sct[1] = tn;
      }
      __syncthreads();
      c = sct[0]; t2 = sct[1];
      av = avn;
    }
  }
}

// ---------------------------------------------------------------------------
extern "C" void kernel_launch(void* const* d_in, const int* in_sizes, int n_in,
                              void* d_out, int out_size, void* d_ws, size_t ws_size,
                              hipStream_t stream)
{
  const float* P  = (const float*)d_in[0];
  const float* Q  = (const float*)d_in[1];
  const float* pi = (const float*)d_in[2];
  const float* T  = (const float*)d_in[3];
  const int*   ls = (const int*)d_in[4];

  float* out = (float*)d_out;

  // ws regions (launch-invariant branches -> graph-safe):
  //   [0, QTFL)        QW  (scan-optimized Q layout)
  //   [QTFL, 2*QTFL)   QT  (backtrace-coalesced Q layout)
  int wsmode = 0; float* QW = nullptr; float* QT = nullptr;
  if (ws_size >= (size_t)QTFL*4){ wsmode = 1; QW = (float*)d_ws; }
  if (ws_size >= (size_t)2*QTFL*4){ wsmode = 2; QT = (float*)d_ws + QTFL; }

  if (wsmode >= 1) qw_kernel<<<JT, 256, 0, stream>>>(Q, QW);
  if (wsmode >= 2) qtrans_kernel<<<81, 256, 0, stream>>>(Q, QT);
  mega_kernel<<<NBATCH, 1024, 0, stream>>>(P, Q, pi, T, ls, out, QW, QT, wsmode);
}